// Round 1
// baseline (233.115 us; speedup 1.0000x reference)
//
#include <hip/hip_runtime.h>
#include <math.h>

// Problem: lkd scan over T=65536 steps, DIM=512, fp32. Closed form:
//   D_t = v + c*t ;  var_t = (v-c) D_t / D_{t-1} ;  mu_t = ((v-c)mu0 + c Z_t)/D_{t-1}
//   Z_t = prefix sum of z over t (per column).
//   lkd = analytic_logdet + Sum_t,d -(z-mu_t)^2 * D_{t-1} / (2 (v-c) D_t)
// Pipeline: K1 chunk colsums -> K2a/K2b 2-level exclusive scan -> K3 main pass.
// Workspace: CHUNKS*DIM + GROUPS*DIM floats = 2MB + 128KB (assumed <= ws_size).

#define DIM    512
#define TT     65536
#define CHUNKS 1024
#define ROWS   64      // TT / CHUNKS
#define GROUPS 64
#define CPG    16      // CHUNKS / GROUPS

#define TWO_PI 6.283185307179586

// K1: per-chunk column sums. grid=CHUNKS, block=256 (2 cols/thread, float2 loads).
__global__ __launch_bounds__(256) void k1_colsum(const float* __restrict__ z,
                                                 float* __restrict__ sums) {
    const int chunk = blockIdx.x;
    const int c2 = threadIdx.x;  // float2 column index 0..255
    const float2* zp = reinterpret_cast<const float2*>(z)
                       + (size_t)chunk * ROWS * (DIM / 2) + c2;
    float sx = 0.f, sy = 0.f;
#pragma unroll 16
    for (int r = 0; r < ROWS; ++r) {
        float2 v = zp[(size_t)r * (DIM / 2)];
        sx += v.x;
        sy += v.y;
    }
    float2* sp = reinterpret_cast<float2*>(sums) + (size_t)chunk * (DIM / 2) + c2;
    *sp = make_float2(sx, sy);
}

// K2a: within-group exclusive scan (in place) + group totals. grid=GROUPS, block=512.
__global__ __launch_bounds__(512) void k2a_scan(float* __restrict__ sums,
                                                float* __restrict__ gsums) {
    const int g = blockIdx.x;
    const int d = threadIdx.x;
    float run = 0.f;
#pragma unroll
    for (int i = 0; i < CPG; ++i) {
        const size_t idx = (size_t)(g * CPG + i) * DIM + d;
        float t = sums[idx];
        sums[idx] = run;
        run += t;
    }
    gsums[(size_t)g * DIM + d] = run;
}

// K2b: exclusive scan over group totals (in place) + analytic log-det term.
__global__ __launch_bounds__(512) void k2b_scan(float* __restrict__ gsums,
                                                const float* __restrict__ var_vbl,
                                                const float* __restrict__ corr_vbl,
                                                float* __restrict__ out) {
    const int d = threadIdx.x;
    float run = 0.f;
#pragma unroll 16
    for (int g = 0; g < GROUPS; ++g) {
        float t = gsums[(size_t)g * DIM + d];
        gsums[(size_t)g * DIM + d] = run;
        run += t;
    }
    // Analytic: sum_t -0.5*log(2pi var_t) telescopes.
    double sp = log1p(exp((double)var_vbl[d]));
    double v = sp * sp;
    double cc = v / (1.0 + exp(-(double)corr_vbl[d]));
    double vmc = v - cc;
    double Dlast = v + cc * (double)(TT - 1);
    double Ld = -0.5 * ((double)TT * (log(TWO_PI) + log(vmc)) + log(Dlast / vmc));
    __shared__ double red[512];
    red[d] = Ld;
    __syncthreads();
    for (int s = 256; s > 0; s >>= 1) {
        if (d < s) red[d] += red[d + s];
        __syncthreads();
    }
    if (d == 0) atomicAdd(out, (float)red[0]);
}

// K3: main pass — quadratic term. grid=CHUNKS, block=256 (2 cols/thread).
__global__ __launch_bounds__(256) void k3_main(const float* __restrict__ z,
                                               const float* __restrict__ sums,
                                               const float* __restrict__ gsums,
                                               const float* __restrict__ var_vbl,
                                               const float* __restrict__ corr_vbl,
                                               const float* __restrict__ prior_mu,
                                               float* __restrict__ out) {
    const int chunk = blockIdx.x;
    const int tid = threadIdx.x;  // 0..255
    const int d0 = tid * 2;
    const int g = chunk / CPG;
    const float t0m1 = (float)(chunk * ROWS) - 1.0f;

    float vv[2], cc[2], k0[2], kq[2], Z[2], Dprev[2], invDprev[2];
#pragma unroll
    for (int j = 0; j < 2; ++j) {
        const int d = d0 + j;
        float spv = log1pf(expf(var_vbl[d]));
        float v = spv * spv;
        float c = v / (1.0f + expf(-corr_vbl[d]));
        float vmc = v - c;
        vv[j] = v;
        cc[j] = c;
        k0[j] = vmc * prior_mu[d];          // (v-c)*mu0
        kq[j] = 0.5f / vmc;
        Z[j] = sums[(size_t)chunk * DIM + d] + gsums[(size_t)g * DIM + d];
        Dprev[j] = fmaf(c, t0m1, v);        // D_{t0-1}
        invDprev[j] = __builtin_amdgcn_rcpf(Dprev[j]);
    }

    const float2* zp = reinterpret_cast<const float2*>(z)
                       + (size_t)chunk * ROWS * (DIM / 2) + tid;
    float acc = 0.f;
    float tf = t0m1 + 1.0f;
#pragma unroll 4
    for (int r = 0; r < ROWS; ++r) {
        float2 zv = zp[(size_t)r * (DIM / 2)];
        float zz[2] = {zv.x, zv.y};
#pragma unroll
        for (int j = 0; j < 2; ++j) {
            float Dt = fmaf(cc[j], tf, vv[j]);            // v + c*t
            float invDt = __builtin_amdgcn_rcpf(Dt);
            float mu = fmaf(cc[j], Z[j], k0[j]) * invDprev[j];
            float e = zz[j] - mu;
            acc = fmaf(e * e * Dprev[j] * invDt, kq[j], acc);
            Z[j] += zz[j];
            Dprev[j] = Dt;
            invDprev[j] = invDt;
        }
        tf += 1.0f;
    }

    // block reduce (4 waves) and subtract from out
    for (int off = 32; off > 0; off >>= 1) acc += __shfl_down(acc, off, 64);
    __shared__ float wsred[4];
    const int lane = tid & 63, w = tid >> 6;
    if (lane == 0) wsred[w] = acc;
    __syncthreads();
    if (tid == 0) atomicAdd(out, -(wsred[0] + wsred[1] + wsred[2] + wsred[3]));
}

extern "C" void kernel_launch(void* const* d_in, const int* in_sizes, int n_in,
                              void* d_out, int out_size, void* d_ws, size_t ws_size,
                              hipStream_t stream) {
    const float* z = (const float*)d_in[0];
    const float* var_vbl = (const float*)d_in[1];
    const float* corr_vbl = (const float*)d_in[2];
    const float* prior_mu = (const float*)d_in[3];
    float* out = (float*)d_out;
    float* sums = (float*)d_ws;                        // CHUNKS*DIM floats (2 MB)
    float* gsums = sums + (size_t)CHUNKS * DIM;        // GROUPS*DIM floats (128 KB)

    hipMemsetAsync(d_out, 0, sizeof(float), stream);
    k1_colsum<<<CHUNKS, 256, 0, stream>>>(z, sums);
    k2a_scan<<<GROUPS, 512, 0, stream>>>(sums, gsums);
    k2b_scan<<<1, 512, 0, stream>>>(gsums, var_vbl, corr_vbl, out);
    k3_main<<<CHUNKS, 256, 0, stream>>>(z, sums, gsums, var_vbl, corr_vbl,
                                        prior_mu, out);
}